// Round 10
// baseline (294.662 us; speedup 1.0000x reference)
//
#include <hip/hip_runtime.h>

// QuantizedConv1d on MI355X (gfx950) — round 10: int8 MFMA datapath
// B=32, CIN=128, L=4096, COUT=256, K=5, replication pad 2.
//   wprep_kernel: W int32 -> fragment-linear i8 wtf[160 frags][64 lanes][16B]
//                 + requant table (sc, off)
//   conv_fused:   256 thr, 4 waves = 2co x 2l, wave = 64co x 64l (acc 4x4).
//                 X quantized to i8 into swizzled LDS (17.4 KB -> 8 blocks/CU),
//                 mfma_i32_16x16x64_i8 swapped (A=X, B=W) -> dwordx4 epilogue.
//                 int32 accumulation is bit-exact vs reference conv.
// Round-9 post-mortem: WRITE ideal, FETCH 40MB, but occupancy 38% / MfmaUtil
// 17% — serialization-bound. i8 halves LDS size (8 blocks/CU co-resident),
// halves ds_read+MFMA counts, halves W traffic.

#define B_    32
#define CIN   128
#define LEN   4096
#define COUT  256
#define KW    5
#define TROWS 136   // staged rows: gl in [l0-4, l0+131]

#define WTF_BYTES (KW * 2 * 16 * 64 * 16)   // 163,840

typedef int            i32x4 __attribute__((ext_vector_type(4)));
typedef float          f32x4v __attribute__((ext_vector_type(4)));
typedef signed char    s8;

// round-half-even(x*20) - 3, clip to [-128,127], as int8.
// (x*20f vs x/0.05f: <=1ulp flips ~1e-6/elem, each moves an output <=0.64 —
// inside the 2.56 absmax threshold; validated passing rounds 6/8/9.)
__device__ __forceinline__ s8 quant_i8(float xv) {
    float q = rintf(xv * 20.0f) - 3.0f;
    q = fminf(fmaxf(q, -128.0f), 127.0f);
    return (s8)(int)q;
}

// W -> fragment-linear i8: frag = k*32 + s*16 + co16; lane holds
// W[co16*16 + (lane&15)][ci = s*64 + (lane>>4)*16 + j], j=0..15.
__global__ __launch_bounds__(256) void wprep_kernel(
        const int* __restrict__ w, const int* __restrict__ bias,
        const float* __restrict__ wscale,
        s8* __restrict__ wtf, float* __restrict__ tbl)
{
    int o    = blockIdx.x * 256 + threadIdx.x;   // 0..10239
    int lane = o & 63, frag = o >> 6;            // frag 0..159
    int k    = frag >> 5;
    int s    = (frag >> 4) & 1;
    int co   = ((frag & 15) << 4) + (lane & 15);
    int ci   = (s << 6) + ((lane >> 4) << 4);
    union { s8 c[16]; i32x4 v; } q;
    #pragma unroll
    for (int j = 0; j < 16; ++j)
        q.c[j] = (s8)w[co * (CIN * KW) + (ci + j) * KW + k];   // |v|<=127
    *(i32x4*)(wtf + (size_t)frag * 1024 + lane * 16) = q.v;

    if (blockIdx.x == 0) {                        // requant table: sc, off
        int c = threadIdx.x;                      // 0..255
        float sc = __fdiv_rn(__fmul_rn(0.05f, wscale[c]), 0.1f);
        tbl[c]       = sc;
        tbl[256 + c] = fmaf((float)bias[c], sc, -128.0f);
    }
}

// Block: 128 co x 128 l, 256 threads, 4 waves = 2co x 2l; wave = 64co x 64l.
// LDS: [136 rows][128 ci] i8, 17,408 B, swizzle: 16B-chunk ^= (row & 7)
// (rows are 128B = exactly 32 banks; slot spread is uniform, volume-limited
// on both write [lane=row stride-1] and read [16 stride-1 rows per lr group]).
// 8 blocks/CU co-resident. Grid 2048 = B x ltile x cohalf, XCD-chunked.
__global__ __launch_bounds__(256, 8) void conv_fused(
        const float* __restrict__ x, const s8* __restrict__ wtf,
        const float* __restrict__ tbl, int* __restrict__ out)
{
    __shared__ __align__(16) s8 smem[TROWS * CIN];   // 17,408 B

    // XCD-contiguous bijective remap (2048 = 8 XCDs x 256): cohalf pairs are
    // consecutive orig ids -> same XCD, adjacent in time (X tile L2 hit).
    int orig  = (blockIdx.x & 7) * 256 + (blockIdx.x >> 3);
    int ch    = orig & 1;
    int ltile = (orig >> 1) & 31;
    int b     = orig >> 6;
    int l0    = ltile << 7;
    int tid   = threadIdx.x;
    int wid   = tid >> 6, lane = tid & 63;
    int lr    = lane & 15, lh = lane >> 4;
    int cog   = (ch << 7) + ((wid & 1) << 6);   // wave co base
    int wl    = (wid >> 1) << 6;                // wave local-l base {0,64}

    const float* xb = x + (size_t)b * CIN * LEN;

    // ---- stage: row r <-> gl = l0 - 4 + r (clamped = replication pad).
    // Lane = row (stride-1): each of the 16 loads is 64 consecutive dwords
    // (coalesced); one b128 LDS write per chunk, conflict-free swizzle.
    for (int p = wid; p < 24; p += 4) {
        int row = ((p >> 3) << 6) + lane;        // rowblock p>>3, chunk c=p&7
        int c   = p & 7;
        if (row < TROWS) {
            int gl = l0 - 4 + row;
            gl = min(max(gl, 0), LEN - 1);
            const float* src = xb + (size_t)(c << 4) * LEN + gl;
            union { s8 cc[16]; i32x4 v; } q;
            #pragma unroll
            for (int j = 0; j < 16; ++j)
                q.cc[j] = quant_i8(src[(size_t)j * LEN]);
            *(i32x4*)(smem + (row << 7) + ((c ^ (row & 7)) << 4)) = q.v;
        }
    }
    __syncthreads();

    // ---- K-loop: 5 taps x 2 ci-halves; 4 af (1KB coalesced, L2-resident) +
    // 4 bf (conflict-free b128) -> 16 mfma_i32_16x16x64_i8.
    // SWAPPED operands (A=X row=l, B=W col=co): D col=co, row=l.
    i32x4 acc[4][4] = {};
    #pragma unroll
    for (int k = 0; k < KW; ++k) {
        #pragma unroll
        for (int s = 0; s < 2; ++s) {
            i32x4 af[4];
            #pragma unroll
            for (int ct = 0; ct < 4; ++ct)
                af[ct] = *(const i32x4*)(
                    wtf + (size_t)((k << 5) + (s << 4) + (cog >> 4) + ct) * 1024 + lane * 16);
            i32x4 bf[4];
            int chunk = (s << 2) + lh;
            #pragma unroll
            for (int lt = 0; lt < 4; ++lt) {
                int row = wl + (lt << 4) + lr + k + 2;
                bf[lt] = *(const i32x4*)(smem + (row << 7) + ((chunk ^ (row & 7)) << 4));
            }
            #pragma unroll
            for (int ct = 0; ct < 4; ++ct)
                #pragma unroll
                for (int lt = 0; lt < 4; ++lt)
                    acc[ct][lt] = __builtin_amdgcn_mfma_i32_16x16x64_i8(
                        bf[lt], af[ct], acc[ct][lt], 0, 0, 0);
        }
    }

    // ---- requant epilogue: col=co=cog+ct*16+lr (per-lane sc/off), row=l.
    // acc[ct][lt] = 4 consecutive l at fixed co -> one dwordx4 store each.
    // (float)int32 is exact (|sum| <= 10.3M < 2^24).
    size_t outb = (size_t)b * COUT * LEN;
    #pragma unroll
    for (int ct = 0; ct < 4; ++ct) {
        int co = cog + (ct << 4) + lr;
        float scv = tbl[co];
        float off = tbl[256 + co];
        int* orow = out + outb + (size_t)co * LEN + l0 + wl + (lh << 2);
        #pragma unroll
        for (int lt = 0; lt < 4; ++lt) {
            i32x4 pk;
            #pragma unroll
            for (int r = 0; r < 4; ++r) {
                float o = rintf(fmaf((float)acc[ct][lt][r], scv, off));
                o = fminf(fmaxf(o, -128.0f), 127.0f);
                pk[r] = (int)o;
            }
            *(i32x4*)(orow + (lt << 4)) = pk;
        }
    }
}

extern "C" void kernel_launch(void* const* d_in, const int* in_sizes, int n_in,
                              void* d_out, int out_size, void* d_ws, size_t ws_size,
                              hipStream_t stream)
{
    const float* x    = (const float*)d_in[0];
    const int*   w    = (const int*)d_in[1];
    const int*   bias = (const int*)d_in[2];
    const float* wsc  = (const float*)d_in[3];
    int* out = (int*)d_out;

    s8*    wtf = (s8*)d_ws;                         // 163,840 B
    float* tbl = (float*)((char*)d_ws + WTF_BYTES); // +2 KB

    wprep_kernel<<<dim3(40), dim3(256), 0, stream>>>(w, bias, wsc, wtf, tbl);
    conv_fused<<<dim3(2048), dim3(256), 0, stream>>>(x, wtf, tbl, out);
}

// Round 11
// 59.648 us; speedup vs baseline: 4.9400x; 4.9400x over previous
//
#include <hip/hip_runtime.h>

// QuantizedConv1d on MI355X (gfx950) — round 11: i8 datapath, FIXED reg cap
// B=32, CIN=128, L=4096, COUT=256, K=5, replication pad 2.
//   wprep_kernel: W int32 -> fragment-linear i8 wtf[160 frags][64 lanes][16B]
//                 + requant table (sc, off)
//   conv_fused:   256 thr, 4 waves = 2co x 2l, wave = 64co x 64l (acc 4x4).
//                 X quantized to i8 into swizzled LDS (17.4 KB),
//                 mfma_i32_16x16x64_i8 swapped (A=X, B=W) -> dwordx4 epilogue.
// Round-10 post-mortem: __launch_bounds__(256,8) = 64-VGPR cap -> acc (64
// regs) spilled to scratch (FETCH 431MB, MfmaUtil 2.8%). i8 LAYOUT was
// verified correct (passed). Fix: (256,4) -> 128-reg cap, ~115 used, 0 spill.

#define B_    32
#define CIN   128
#define LEN   4096
#define COUT  256
#define KW    5
#define TROWS 136   // staged rows: gl in [l0-4, l0+131]

#define WTF_BYTES (KW * 2 * 16 * 64 * 16)   // 163,840

typedef int            i32x4 __attribute__((ext_vector_type(4)));
typedef signed char    s8;

// round-half-even(x*20) - 3, clip to [-128,127], as int8.
// (x*20f vs x/0.05f: <=1ulp flips ~1e-6/elem, each moves an output <=0.64 —
// inside the 2.56 absmax threshold; validated passing rounds 6/8/9/10.)
__device__ __forceinline__ s8 quant_i8(float xv) {
    float q = rintf(xv * 20.0f) - 3.0f;
    q = fminf(fmaxf(q, -128.0f), 127.0f);
    return (s8)(int)q;
}

// W -> fragment-linear i8: frag = k*32 + s*16 + co16; lane holds
// W[co16*16 + (lane&15)][ci = s*64 + (lane>>4)*16 + j], j=0..15.
__global__ __launch_bounds__(256) void wprep_kernel(
        const int* __restrict__ w, const int* __restrict__ bias,
        const float* __restrict__ wscale,
        s8* __restrict__ wtf, float* __restrict__ tbl)
{
    int o    = blockIdx.x * 256 + threadIdx.x;   // 0..10239
    int lane = o & 63, frag = o >> 6;            // frag 0..159
    int k    = frag >> 5;
    int s    = (frag >> 4) & 1;
    int co   = ((frag & 15) << 4) + (lane & 15);
    int ci   = (s << 6) + ((lane >> 4) << 4);
    union { s8 c[16]; i32x4 v; } q;
    #pragma unroll
    for (int j = 0; j < 16; ++j)
        q.c[j] = (s8)w[co * (CIN * KW) + (ci + j) * KW + k];   // |v|<=127
    *(i32x4*)(wtf + (size_t)frag * 1024 + lane * 16) = q.v;

    if (blockIdx.x == 0) {                        // requant table: sc, off
        int c = threadIdx.x;                      // 0..255
        float sc = __fdiv_rn(__fmul_rn(0.05f, wscale[c]), 0.1f);
        tbl[c]       = sc;
        tbl[256 + c] = fmaf((float)bias[c], sc, -128.0f);
    }
}

// Block: 128 co x 128 l, 256 threads, 4 waves = 2co x 2l; wave = 64co x 64l.
// LDS: [136 rows][128 ci] i8, 17,408 B, swizzle: 16B-chunk ^= (row & 7)
// (conflict-free both sides — round-10 PMC showed 0 conflicts).
// Grid 2048 = B x ltile x cohalf, XCD-chunked remap.
__global__ __launch_bounds__(256, 4) void conv_fused(
        const float* __restrict__ x, const s8* __restrict__ wtf,
        const float* __restrict__ tbl, int* __restrict__ out)
{
    __shared__ __align__(16) s8 smem[TROWS * CIN];   // 17,408 B

    // XCD-contiguous bijective remap (2048 = 8 XCDs x 256): cohalf pairs are
    // consecutive orig ids -> same XCD, adjacent in time (X tile L2 hit).
    int orig  = (blockIdx.x & 7) * 256 + (blockIdx.x >> 3);
    int ch    = orig & 1;
    int ltile = (orig >> 1) & 31;
    int b     = orig >> 6;
    int l0    = ltile << 7;
    int tid   = threadIdx.x;
    int wid   = tid >> 6, lane = tid & 63;
    int lr    = lane & 15, lh = lane >> 4;
    int cog   = (ch << 7) + ((wid & 1) << 6);   // wave co base
    int wl    = (wid >> 1) << 6;                // wave local-l base {0,64}

    const float* xb = x + (size_t)b * CIN * LEN;

    // ---- stage: row r <-> gl = l0 - 4 + r (clamped = replication pad).
    // Lane = row (stride-1): each load is 64 consecutive dwords (coalesced);
    // one b128 LDS write per 16-ci chunk, conflict-free swizzle.
    for (int p = wid; p < 24; p += 4) {
        int row = ((p >> 3) << 6) + lane;        // rowblock p>>3, chunk c=p&7
        int c   = p & 7;
        if (row < TROWS) {
            int gl = l0 - 4 + row;
            gl = min(max(gl, 0), LEN - 1);
            const float* src = xb + (size_t)(c << 4) * LEN + gl;
            union { s8 cc[16]; i32x4 v; } q;
            #pragma unroll
            for (int j = 0; j < 16; ++j)
                q.cc[j] = quant_i8(src[(size_t)j * LEN]);
            *(i32x4*)(smem + (row << 7) + ((c ^ (row & 7)) << 4)) = q.v;
        }
    }
    __syncthreads();

    // ---- K-loop: 5 taps x 2 ci-halves; 4 af (1KB coalesced, L2-resident) +
    // 4 bf (conflict-free b128) -> 16 mfma_i32_16x16x64_i8.
    // SWAPPED operands (A=X row=l, B=W col=co): D col=co, row=l.
    i32x4 acc[4][4] = {};
    #pragma unroll
    for (int k = 0; k < KW; ++k) {
        #pragma unroll
        for (int s = 0; s < 2; ++s) {
            i32x4 af[4];
            #pragma unroll
            for (int ct = 0; ct < 4; ++ct)
                af[ct] = *(const i32x4*)(
                    wtf + (size_t)((k << 5) + (s << 4) + (cog >> 4) + ct) * 1024 + lane * 16);
            i32x4 bf[4];
            int chunk = (s << 2) + lh;
            #pragma unroll
            for (int lt = 0; lt < 4; ++lt) {
                int row = wl + (lt << 4) + lr + k + 2;
                bf[lt] = *(const i32x4*)(smem + (row << 7) + ((chunk ^ (row & 7)) << 4));
            }
            #pragma unroll
            for (int ct = 0; ct < 4; ++ct)
                #pragma unroll
                for (int lt = 0; lt < 4; ++lt)
                    acc[ct][lt] = __builtin_amdgcn_mfma_i32_16x16x64_i8(
                        bf[lt], af[ct], acc[ct][lt], 0, 0, 0);
        }
    }

    // ---- requant epilogue: col=co=cog+ct*16+lr (per-lane sc/off), row=l.
    // acc[ct][lt] = 4 consecutive l at fixed co -> one dwordx4 store each.
    // (float)int32 is exact (|sum| <= 10.3M < 2^24).
    size_t outb = (size_t)b * COUT * LEN;
    #pragma unroll
    for (int ct = 0; ct < 4; ++ct) {
        int co = cog + (ct << 4) + lr;
        float scv = tbl[co];
        float off = tbl[256 + co];
        int* orow = out + outb + (size_t)co * LEN + l0 + wl + (lh << 2);
        #pragma unroll
        for (int lt = 0; lt < 4; ++lt) {
            i32x4 pk;
            #pragma unroll
            for (int r = 0; r < 4; ++r) {
                float o = rintf(fmaf((float)acc[ct][lt][r], scv, off));
                o = fminf(fmaxf(o, -128.0f), 127.0f);
                pk[r] = (int)o;
            }
            *(i32x4*)(orow + (lt << 4)) = pk;
        }
    }
}

extern "C" void kernel_launch(void* const* d_in, const int* in_sizes, int n_in,
                              void* d_out, int out_size, void* d_ws, size_t ws_size,
                              hipStream_t stream)
{
    const float* x    = (const float*)d_in[0];
    const int*   w    = (const int*)d_in[1];
    const int*   bias = (const int*)d_in[2];
    const float* wsc  = (const float*)d_in[3];
    int* out = (int*)d_out;

    s8*    wtf = (s8*)d_ws;                         // 163,840 B
    float* tbl = (float*)((char*)d_ws + WTF_BYTES); // +2 KB

    wprep_kernel<<<dim3(40), dim3(256), 0, stream>>>(w, bias, wsc, wtf, tbl);
    conv_fused<<<dim3(2048), dim3(256), 0, stream>>>(x, wtf, tbl, out);
}